// Round 1
// baseline (185.818 us; speedup 1.0000x reference)
//
#include <hip/hip_runtime.h>

// ANOVA kernel order 3:  out[b] = sum_e e3(x[b, :, e])
// x: (8192, 64, 64) fp32, row-major, e innermost.
// Per-(b,e) DP over fields f: s3 += s2*v; s2 += s1*v; s1 += v.
// Memory-bound: 128 MiB read once -> floor ~21 us at 6.3 TB/s.

constexpr int BATCH = 8192;
constexpr int NFIELD = 64;
constexpr int NEMB = 64;

__global__ __launch_bounds__(256) void anova3_kernel(const float* __restrict__ x,
                                                     float* __restrict__ out) {
    const int tid = blockIdx.x * 256 + threadIdx.x;
    const int b = tid >> 4;          // 16 threads per batch row
    const int g = tid & 15;          // float4 group within the 64-wide embedding

    const float4* xp = reinterpret_cast<const float4*>(x)
                     + (size_t)b * (NFIELD * NEMB / 4) + g;

    float4 s1 = make_float4(0.f, 0.f, 0.f, 0.f);
    float4 s2 = make_float4(0.f, 0.f, 0.f, 0.f);
    float4 s3 = make_float4(0.f, 0.f, 0.f, 0.f);

#pragma unroll 16
    for (int f = 0; f < NFIELD; ++f) {
        float4 v = xp[(size_t)f * (NEMB / 4)];
        // update order matters: s3 uses old s2, s2 uses old s1
        s3.x = fmaf(s2.x, v.x, s3.x); s2.x = fmaf(s1.x, v.x, s2.x); s1.x += v.x;
        s3.y = fmaf(s2.y, v.y, s3.y); s2.y = fmaf(s1.y, v.y, s2.y); s1.y += v.y;
        s3.z = fmaf(s2.z, v.z, s3.z); s2.z = fmaf(s1.z, v.z, s2.z); s1.z += v.z;
        s3.w = fmaf(s2.w, v.w, s3.w); s2.w = fmaf(s1.w, v.w, s2.w); s1.w += v.w;
    }

    float r = (s3.x + s3.y) + (s3.z + s3.w);
    // reduce across the 16-lane group (xor offsets stay within the group)
    r += __shfl_xor(r, 8);
    r += __shfl_xor(r, 4);
    r += __shfl_xor(r, 2);
    r += __shfl_xor(r, 1);

    if (g == 0) out[b] = r;
}

extern "C" void kernel_launch(void* const* d_in, const int* in_sizes, int n_in,
                              void* d_out, int out_size, void* d_ws, size_t ws_size,
                              hipStream_t stream) {
    const float* x = (const float*)d_in[0];
    float* out = (float*)d_out;
    const int total_threads = BATCH * 16;        // 131072
    dim3 grid(total_threads / 256);              // 512 blocks
    anova3_kernel<<<grid, dim3(256), 0, stream>>>(x, out);
}